// Round 8
// baseline (246.233 us; speedup 1.0000x reference)
//
#include <hip/hip_runtime.h>

#define ALPHA 0.2f
#define BB 4
#define NN 2048
#define IC 256
#define OC 32
#define TI 8                      // i-rows per k3 block (one wave per row)

// ---------------------------------------------------------------------------
// Kernel 1 (frozen, r4 form): h = features @ W; f1 = h@a[:OC]; f2 = h@a[OC:]
// ---------------------------------------------------------------------------
__global__ void k1_hproj(const float* __restrict__ feat,
                         const float* __restrict__ W,
                         const float* __restrict__ a,
                         float* __restrict__ h,
                         float* __restrict__ f1,
                         float* __restrict__ f2) {
    __shared__ float s_feat[IC];
    int row = blockIdx.x;           // b*N + n
    int tid = threadIdx.x;          // 0..63
    ((float4*)s_feat)[tid] = ((const float4*)(feat + (size_t)row * IC))[tid];
    __syncthreads();
    if (tid < OC) {
        int c = tid;
        float acc = 0.f;
        #pragma unroll 8
        for (int k = 0; k < IC; ++k)
            acc += s_feat[k] * W[k * OC + c];
        h[(size_t)row * OC + c] = acc;
        float v1 = acc * a[c];
        float v2 = acc * a[OC + c];
        #pragma unroll
        for (int m = 16; m >= 1; m >>= 1) {
            v1 += __shfl_xor(v1, m, 64);
            v2 += __shfl_xor(v2, m, 64);
        }
        if (c == 0) { f1[row] = v1; f2[row] = v2; }
    }
}

// ---------------------------------------------------------------------------
// Kernel 2 (REWRITTEN): cij[i,j] = sum_c distance[i,j,c] * We[c]
// Lane-per-element: each thread reads its own 128B row via 8 INDEPENDENT
// float4 loads (no shuffles, no masked stores, no lgkm stalls in the loop).
// We[] is wave-uniform -> compiler scalarizes to s_loads; dot uses SGPR srcs.
// Grid-stride 2048x256 = m13's measured-6.3TB/s config.
// ---------------------------------------------------------------------------
__global__ void k2_cij(const float* __restrict__ distance,
                       const float* __restrict__ We,
                       float* __restrict__ cij) {
    const float4 w0 = ((const float4*)We)[0];
    const float4 w1 = ((const float4*)We)[1];
    const float4 w2 = ((const float4*)We)[2];
    const float4 w3 = ((const float4*)We)[3];
    const float4 w4 = ((const float4*)We)[4];
    const float4 w5 = ((const float4*)We)[5];
    const float4 w6 = ((const float4*)We)[6];
    const float4 w7 = ((const float4*)We)[7];
    size_t e = (size_t)blockIdx.x * blockDim.x + threadIdx.x;
    const size_t stride = (size_t)gridDim.x * blockDim.x;
    const size_t total = (size_t)NN * NN;
    const float4* d4 = (const float4*)distance;
    for (; e < total; e += stride) {
        const float4* row = d4 + e * 8;
        float4 d0 = row[0], d1 = row[1], d2 = row[2], d3 = row[3];
        float4 d4v = row[4], d5 = row[5], d6 = row[6], d7 = row[7];
        float acc = d0.x * w0.x + d0.y * w0.y + d0.z * w0.z + d0.w * w0.w
                  + d1.x * w1.x + d1.y * w1.y + d1.z * w1.z + d1.w * w1.w
                  + d2.x * w2.x + d2.y * w2.y + d2.z * w2.z + d2.w * w2.w
                  + d3.x * w3.x + d3.y * w3.y + d3.z * w3.z + d3.w * w3.w
                  + d4v.x * w4.x + d4v.y * w4.y + d4v.z * w4.z + d4v.w * w4.w
                  + d5.x * w5.x + d5.y * w5.y + d5.z * w5.z + d5.w * w5.w
                  + d6.x * w6.x + d6.y * w6.y + d6.z * w6.z + d6.w * w6.w
                  + d7.x * w7.x + d7.y * w7.y + d7.z * w7.z + d7.w * w7.w;
        cij[e] = acc;
    }
}

// ---------------------------------------------------------------------------
// Kernel 3 (frozen, r6 form, measured 57.3 us): fp16 p-tile, f2 in LDS.
// ---------------------------------------------------------------------------
__global__ void k3_attn(const float* __restrict__ f1,
                        const float* __restrict__ f2,
                        const float* __restrict__ h,
                        const float* __restrict__ cij,
                        const int* __restrict__ adj,
                        float* __restrict__ out) {
    __shared__ _Float16 s_p[TI][NN];       // 32 KB
    __shared__ float s_f2[NN];             // 8 KB
    __shared__ float s_den[TI];
    __shared__ float s_fin[8][8][TI][4];   // 8 KB
    int bt = blockIdx.x;                   // 0..1023
    int b  = bt >> 8;                      // NN/TI = 256 tiles
    int i0 = (bt & 255) * TI;
    int tid = threadIdx.x;                 // 0..511
    int wv = tid >> 6;
    int lane = tid & 63;

    ((float4*)s_f2)[tid] = ((const float4*)(f2 + (size_t)b * NN))[tid];
    __syncthreads();

    {
        int i  = i0 + wv;
        int bi = b * NN + i;
        float f1i = f1[bi];
        const int*   adjrow = adj + (size_t)i * NN;
        const float* cijrow = cij + (size_t)i * NN;
        float sc[NN / 64];
        float lmax = -1e30f;
        #pragma unroll
        for (int k = 0; k < NN / 64; ++k) {
            int j = lane + 64 * k;
            float e = f1i + s_f2[j];
            e = e > 0.f ? e : ALPHA * e;
            float s = ((adjrow[j] > 0) || (j == i)) ? (e + cijrow[j]) : -1e30f;
            sc[k] = s;
            lmax = fmaxf(lmax, s);
        }
        #pragma unroll
        for (int m = 32; m >= 1; m >>= 1) lmax = fmaxf(lmax, __shfl_xor(lmax, m, 64));
        float lsum = 0.f;
        #pragma unroll
        for (int k = 0; k < NN / 64; ++k) {
            float p = __expf(sc[k] - lmax);
            s_p[wv][lane + 64 * k] = (_Float16)p;
            lsum += p;
        }
        #pragma unroll
        for (int m = 32; m >= 1; m >>= 1) lsum += __shfl_xor(lsum, m, 64);
        if (lane == 0) s_den[wv] = lsum;
    }
    __syncthreads();

    const float* hb = h + (size_t)b * NN * OC;
    int g  = tid >> 3;          // 0..63
    int c4 = tid & 7;           // 0..7
    float acc[TI][4];
    #pragma unroll
    for (int r = 0; r < TI; ++r) { acc[r][0] = acc[r][1] = acc[r][2] = acc[r][3] = 0.f; }
    #pragma unroll 4
    for (int k = 0; k < NN / 64; ++k) {
        int j = g + 64 * k;
        float4 hv = *(const float4*)(hb + (size_t)j * OC + c4 * 4);
        #pragma unroll
        for (int r = 0; r < TI; ++r) {
            float p = (float)s_p[r][j];
            acc[r][0] += p * hv.x;
            acc[r][1] += p * hv.y;
            acc[r][2] += p * hv.z;
            acc[r][3] += p * hv.w;
        }
    }
    #pragma unroll
    for (int r = 0; r < TI; ++r) {
        #pragma unroll
        for (int q = 0; q < 4; ++q) {
            float v = acc[r][q];
            v += __shfl_xor(v, 8, 64);
            v += __shfl_xor(v, 16, 64);
            v += __shfl_xor(v, 32, 64);
            acc[r][q] = v;
        }
    }
    if ((tid & 56) == 0) {
        #pragma unroll
        for (int r = 0; r < TI; ++r)
            #pragma unroll
            for (int q = 0; q < 4; ++q)
                s_fin[wv][c4][r][q] = acc[r][q];
    }
    __syncthreads();
    if (tid < TI * OC) {
        int r = tid >> 5, c = tid & 31;
        float v = 0.f;
        #pragma unroll
        for (int wq = 0; wq < 8; ++wq) v += s_fin[wq][c >> 2][r][c & 3];
        out[((size_t)b * NN + i0 + r) * OC + c] = v / s_den[r];
    }
}

extern "C" void kernel_launch(void* const* d_in, const int* in_sizes, int n_in,
                              void* d_out, int out_size, void* d_ws, size_t ws_size,
                              hipStream_t stream) {
    const float* feat     = (const float*)d_in[0];  // [B,N,IC]
    const float* W        = (const float*)d_in[1];  // [IC,OC]
    const float* a        = (const float*)d_in[2];  // [2*OC,1]
    const float* We       = (const float*)d_in[3];  // [OC,1]
    const float* distance = (const float*)d_in[4];  // [N,N,OC]
    const int*   adj      = (const int*)d_in[5];    // [N,N]
    float* out = (float*)d_out;

    float* ws  = (float*)d_ws;
    float* h   = ws;                       // B*N*OC
    float* f1  = h  + (size_t)BB * NN * OC;
    float* f2  = f1 + (size_t)BB * NN;
    float* cij = f2 + (size_t)BB * NN;     // N*N

    k1_hproj<<<BB * NN, 64, 0, stream>>>(feat, W, a, h, f1, f2);
    k2_cij<<<2048, 256, 0, stream>>>(distance, We, cij);
    k3_attn<<<BB * NN / TI, 512, 0, stream>>>(f1, f2, h, cij, adj, out);
}

// Round 9
// 191.708 us; speedup vs baseline: 1.2844x; 1.2844x over previous
//
#include <hip/hip_runtime.h>

#define ALPHA 0.2f
#define BB 4
#define NN 2048
#define IC 256
#define OC 32
#define TI 8                      // i-rows per k3 block (one wave per row)

// ---------------------------------------------------------------------------
// Kernel 1 (frozen, r4 form): h = features @ W; f1 = h@a[:OC]; f2 = h@a[OC:]
// ---------------------------------------------------------------------------
__global__ void k1_hproj(const float* __restrict__ feat,
                         const float* __restrict__ W,
                         const float* __restrict__ a,
                         float* __restrict__ h,
                         float* __restrict__ f1,
                         float* __restrict__ f2) {
    __shared__ float s_feat[IC];
    int row = blockIdx.x;           // b*N + n
    int tid = threadIdx.x;          // 0..63
    ((float4*)s_feat)[tid] = ((const float4*)(feat + (size_t)row * IC))[tid];
    __syncthreads();
    if (tid < OC) {
        int c = tid;
        float acc = 0.f;
        #pragma unroll 8
        for (int k = 0; k < IC; ++k)
            acc += s_feat[k] * W[k * OC + c];
        h[(size_t)row * OC + c] = acc;
        float v1 = acc * a[c];
        float v2 = acc * a[OC + c];
        #pragma unroll
        for (int m = 16; m >= 1; m >>= 1) {
            v1 += __shfl_xor(v1, m, 64);
            v2 += __shfl_xor(v2, m, 64);
        }
        if (c == 0) { f1[row] = v1; f2[row] = v2; }
    }
}

// ---------------------------------------------------------------------------
// Kernel 2 (r4 reads + COALESCED STORES): cij[i,j] = sum_c distance[i,j,c]*We[c]
// Reads: 8 lanes/elem, consecutive float4 per wave-instr (1KB contiguous) --
// the r4 pattern, proven fastest. 8 independent preloads deepen the pipeline.
// Stores: results batched in LDS (64/wave), flushed as one 256B full-density
// wave store. Theory: r4's 1/8-density masked stores cost ~40us in
// partial-line write-allocate traffic; this removes it.
// ---------------------------------------------------------------------------
__global__ void k2_cij(const float* __restrict__ distance,
                       const float* __restrict__ We,
                       float* __restrict__ cij) {
    __shared__ float s_res[4][64];
    int tid  = threadIdx.x;          // 0..255
    int wv   = tid >> 6;             // wave 0..3
    int lane = tid & 63;
    int g    = lane >> 3;            // 0..7: element group within wave
    int r    = lane & 7;             // float4 slot within element
    float4 w = ((const float4*)We)[r];
    const float4* d4 = (const float4*)distance;
    const size_t total = (size_t)NN * NN;            // 4,194,304
    // 8192 blocks x 256 elems/tile -> exactly 2 uniform tiles per block
    for (size_t tb = (size_t)blockIdx.x * 256; tb < total;
         tb += (size_t)gridDim.x * 256) {
        size_t wbase = tb + (size_t)wv * 64;
        // preload 8 independent float4s (one per 8-elem sub-iteration)
        float4 d[8];
        #pragma unroll
        for (int it = 0; it < 8; ++it)
            d[it] = d4[(wbase + it * 8 + g) * 8 + r];
        #pragma unroll
        for (int it = 0; it < 8; ++it) {
            float v = d[it].x * w.x + d[it].y * w.y + d[it].z * w.z + d[it].w * w.w;
            v += __shfl_xor(v, 1, 64);
            v += __shfl_xor(v, 2, 64);
            v += __shfl_xor(v, 4, 64);
            if (r == 0) s_res[wv][it * 8 + g] = v;   // 8 distinct banks, no conflict
        }
        __syncthreads();                             // uniform trip count: legal
        cij[wbase + lane] = s_res[wv][lane];         // 256B/wave, full density
        __syncthreads();
    }
}

// ---------------------------------------------------------------------------
// Kernel 3 (frozen, r6 form, measured 57.3 us): fp16 p-tile, f2 in LDS.
// ---------------------------------------------------------------------------
__global__ void k3_attn(const float* __restrict__ f1,
                        const float* __restrict__ f2,
                        const float* __restrict__ h,
                        const float* __restrict__ cij,
                        const int* __restrict__ adj,
                        float* __restrict__ out) {
    __shared__ _Float16 s_p[TI][NN];       // 32 KB
    __shared__ float s_f2[NN];             // 8 KB
    __shared__ float s_den[TI];
    __shared__ float s_fin[8][8][TI][4];   // 8 KB
    int bt = blockIdx.x;                   // 0..1023
    int b  = bt >> 8;                      // NN/TI = 256 tiles
    int i0 = (bt & 255) * TI;
    int tid = threadIdx.x;                 // 0..511
    int wv = tid >> 6;
    int lane = tid & 63;

    ((float4*)s_f2)[tid] = ((const float4*)(f2 + (size_t)b * NN))[tid];
    __syncthreads();

    {
        int i  = i0 + wv;
        int bi = b * NN + i;
        float f1i = f1[bi];
        const int*   adjrow = adj + (size_t)i * NN;
        const float* cijrow = cij + (size_t)i * NN;
        float sc[NN / 64];
        float lmax = -1e30f;
        #pragma unroll
        for (int k = 0; k < NN / 64; ++k) {
            int j = lane + 64 * k;
            float e = f1i + s_f2[j];
            e = e > 0.f ? e : ALPHA * e;
            float s = ((adjrow[j] > 0) || (j == i)) ? (e + cijrow[j]) : -1e30f;
            sc[k] = s;
            lmax = fmaxf(lmax, s);
        }
        #pragma unroll
        for (int m = 32; m >= 1; m >>= 1) lmax = fmaxf(lmax, __shfl_xor(lmax, m, 64));
        float lsum = 0.f;
        #pragma unroll
        for (int k = 0; k < NN / 64; ++k) {
            float p = __expf(sc[k] - lmax);
            s_p[wv][lane + 64 * k] = (_Float16)p;
            lsum += p;
        }
        #pragma unroll
        for (int m = 32; m >= 1; m >>= 1) lsum += __shfl_xor(lsum, m, 64);
        if (lane == 0) s_den[wv] = lsum;
    }
    __syncthreads();

    const float* hb = h + (size_t)b * NN * OC;
    int g  = tid >> 3;          // 0..63
    int c4 = tid & 7;           // 0..7
    float acc[TI][4];
    #pragma unroll
    for (int r = 0; r < TI; ++r) { acc[r][0] = acc[r][1] = acc[r][2] = acc[r][3] = 0.f; }
    #pragma unroll 4
    for (int k = 0; k < NN / 64; ++k) {
        int j = g + 64 * k;
        float4 hv = *(const float4*)(hb + (size_t)j * OC + c4 * 4);
        #pragma unroll
        for (int r = 0; r < TI; ++r) {
            float p = (float)s_p[r][j];
            acc[r][0] += p * hv.x;
            acc[r][1] += p * hv.y;
            acc[r][2] += p * hv.z;
            acc[r][3] += p * hv.w;
        }
    }
    #pragma unroll
    for (int r = 0; r < TI; ++r) {
        #pragma unroll
        for (int q = 0; q < 4; ++q) {
            float v = acc[r][q];
            v += __shfl_xor(v, 8, 64);
            v += __shfl_xor(v, 16, 64);
            v += __shfl_xor(v, 32, 64);
            acc[r][q] = v;
        }
    }
    if ((tid & 56) == 0) {
        #pragma unroll
        for (int r = 0; r < TI; ++r)
            #pragma unroll
            for (int q = 0; q < 4; ++q)
                s_fin[wv][c4][r][q] = acc[r][q];
    }
    __syncthreads();
    if (tid < TI * OC) {
        int r = tid >> 5, c = tid & 31;
        float v = 0.f;
        #pragma unroll
        for (int wq = 0; wq < 8; ++wq) v += s_fin[wq][c >> 2][r][c & 3];
        out[((size_t)b * NN + i0 + r) * OC + c] = v / s_den[r];
    }
}

extern "C" void kernel_launch(void* const* d_in, const int* in_sizes, int n_in,
                              void* d_out, int out_size, void* d_ws, size_t ws_size,
                              hipStream_t stream) {
    const float* feat     = (const float*)d_in[0];  // [B,N,IC]
    const float* W        = (const float*)d_in[1];  // [IC,OC]
    const float* a        = (const float*)d_in[2];  // [2*OC,1]
    const float* We       = (const float*)d_in[3];  // [OC,1]
    const float* distance = (const float*)d_in[4];  // [N,N,OC]
    const int*   adj      = (const int*)d_in[5];    // [N,N]
    float* out = (float*)d_out;

    float* ws  = (float*)d_ws;
    float* h   = ws;                       // B*N*OC
    float* f1  = h  + (size_t)BB * NN * OC;
    float* f2  = f1 + (size_t)BB * NN;
    float* cij = f2 + (size_t)BB * NN;     // N*N

    k1_hproj<<<BB * NN, 64, 0, stream>>>(feat, W, a, h, f1, f2);
    k2_cij<<<8192, 256, 0, stream>>>(distance, We, cij);
    k3_attn<<<BB * NN / TI, 512, 0, stream>>>(f1, f2, h, cij, adj, out);
}